// Round 6
// baseline (366.018 us; speedup 1.0000x reference)
//
#include <hip/hip_runtime.h>
#include <hip/hip_bf16.h>

// CustomBernsteinLayer: out[b,o] = sum_{i,k} ber[b,i,k] * (coeffs[o,i,k]*weights[o,i])
// ber = (1+t)^k (1-t)^(8-k), t = tanh(x).  With e = exp2(2x*log2e):
//   (1-t) = 2/(e+1) = q, ratio r = e, p0 = q^8, ber_{k+1} = ber_k * r.
// bf16 MFMA GEMM M=16384 N=256 K=2304, barrier-free per-lane A-gen.
// Round 6: LOW-VGPR redesign for real occupancy. Wave owns 16 rows x 64 cols
// (p/r state halves vs R5); total live state ~124 VGPR < 128 cap from
// __launch_bounds__(256,4) -> 4 waves/SIMD (2x R5), no spill.
// Block = 4 waves stacked in M (64 rows x 64 cols); grid = 256 rowgroups x 4
// col-groups; cg = blk>>8 so co-resident blocks share identical B addresses.

#define BDIM 16384
#define IDIM 256
#define ODIM 256
#define NK 9
#define NCHUNK 4
#define NSTEP 36
#define STEP_ELEMS (ODIM * 64)   // 16384 bf16 (32 KB) per K-step block

typedef short short8 __attribute__((ext_vector_type(8)));
typedef float floatx4 __attribute__((ext_vector_type(4)));

// ---------------------------------------------------------------------------
// prep (validated): wc[step][e] = bf16(coeffs[o,i,k]*weights[o,i]),
// e = (((o>>4)*2 + s)*64 + (o&15) + quad*16)*8 + j, i_local = s*32+quad*8+j,
// step = (i>>6)*9 + k. One coalesced 16B store per thread.
// ---------------------------------------------------------------------------
__global__ __launch_bounds__(256) void prep_wc2(const float* __restrict__ weights,
                                                const float* __restrict__ coeffs,
                                                ushort* __restrict__ wc) {
    int idx  = blockIdx.x * 256 + threadIdx.x;  // 73728 chunks
    int step = idx >> 11;
    int c    = idx & 2047;
    int big    = c >> 6;
    int lane_w = c & 63;
    int o    = (big >> 1) * 16 + (lane_w & 15);
    int s    = big & 1;
    int quad = lane_w >> 4;
    int ic = step / 9;
    int k  = step - ic * 9;
    int i0 = ic * 64 + s * 32 + quad * 8;

    const float* cp = coeffs + (size_t)(o * IDIM + i0) * NK + k;
    float4 w0 = *(const float4*)(weights + o * IDIM + i0);
    float4 w1 = *(const float4*)(weights + o * IDIM + i0 + 4);
    float wv[8] = {w0.x, w0.y, w0.z, w0.w, w1.x, w1.y, w1.z, w1.w};

    union { ushort us[8]; int4 v; __hip_bfloat162 h2[4]; } pk;
#pragma unroll
    for (int j = 0; j < 8; j += 2) {
        float a = cp[(size_t)j * NK] * wv[j];
        float b = cp[(size_t)(j + 1) * NK] * wv[j + 1];
        pk.h2[j >> 1] = __float22bfloat162_rn(make_float2(a, b));
    }
    *(int4*)(wc + (size_t)step * STEP_ELEMS + (size_t)c * 8) = pk.v;
}

// ---------------------------------------------------------------------------
// GEMM: 1024 blocks x 256 threads (4 waves).
//   cg = blockIdx.x >> 8  -> cols cg*64 .. +63 (shared by whole block, and by
//                            all co-resident blocks -> L1/L2 friendly)
//   rg = blockIdx.x & 255 -> wave w covers rows rg*64 + w*16 .. +15
// Per-lane state: row = rb + (lane&15); i_local = s*32 + (lane>>4)*8 + j.
//   p[2][8], r[2][8] (basis recurrence), bfr dbuf [2][2][4], acc[4].
// No LDS, no barriers; ~124 VGPR -> 4 waves/SIMD.
// ---------------------------------------------------------------------------
__global__ __launch_bounds__(256, 4) void bern_gemm(const float* __restrict__ x,
                                                    const ushort* __restrict__ wc,
                                                    float* __restrict__ out) {
    const int tid  = threadIdx.x;
    const int wave = tid >> 6;
    const int lane = tid & 63;
    const int cg   = blockIdx.x >> 8;
    const int rb   = (blockIdx.x & 255) * 64 + wave * 16;
    const int lrow = lane & 15;
    const int jseg = (lane >> 4) * 8;      // 0,8,16,24

    float p[2][8];      // [s][j]: raw x at chunk boundary, then running ber
    float r[2][8];      // ratio e = exp2(2x log2 e)
    floatx4 acc[4];
    floatx4 zero = {0.0f, 0.0f, 0.0f, 0.0f};
#pragma unroll
    for (int n = 0; n < 4; ++n) acc[n] = zero;

#define LOAD_X(ic_)                                                             \
    {                                                                           \
        _Pragma("unroll") for (int s = 0; s < 2; ++s) {                         \
            const float* xp = x + (size_t)(rb + lrow) * IDIM                    \
                              + (ic_) * 64 + s * 32 + jseg;                     \
            float4 v0 = *(const float4*)(xp);                                   \
            float4 v1 = *(const float4*)(xp + 4);                               \
            p[s][0] = v0.x; p[s][1] = v0.y; p[s][2] = v0.z; p[s][3] = v0.w;     \
            p[s][4] = v1.x; p[s][5] = v1.y; p[s][6] = v1.z; p[s][7] = v1.w;     \
        }                                                                       \
    }

#define SETUP_BASIS()                                                           \
    {                                                                           \
        _Pragma("unroll") for (int s = 0; s < 2; ++s)                           \
        _Pragma("unroll") for (int e = 0; e < 8; ++e) {                         \
            float t  = __builtin_amdgcn_exp2f(p[s][e] * 2.8853900817779268f);   \
            float q  = 2.0f * __builtin_amdgcn_rcpf(t + 1.0f);                  \
            float q2 = q * q;                                                   \
            float q4 = q2 * q2;                                                 \
            p[s][e] = q4 * q4;                                                  \
            r[s][e] = t;                                                        \
        }                                                                       \
    }

    LOAD_X(0);
    SETUP_BASIS();

    // B fragment byte offset (within a step block) for (n, s):
    //   (((cg*4 + n)*2 + s)*64 + lane) * 16 bytes
    const ushort* wbase = wc + ((size_t)(cg * 8) * 64 + lane) * 8;
    // frag(n,s) at wbase + (n*2+s)*512 elements (=1024 B)

    // ---- B register double-buffer; preload step 0 ----
    short8 bfr[2][2][4];   // [buf][s][n]
#pragma unroll
    for (int s = 0; s < 2; ++s)
#pragma unroll
        for (int n = 0; n < 4; ++n)
            bfr[0][s][n] = *(const short8*)(wbase + (n * 2 + s) * 512);

    for (int ic = 0; ic < NCHUNK; ++ic) {
        const ushort* wchunk = wbase + (size_t)ic * NK * STEP_ELEMS;
#pragma unroll
        for (int k = 0; k < NK; ++k) {
            const int step = ic * NK + k;
            const int cur  = step & 1;
            const int nxt  = cur ^ 1;

            // prefetch next step's B fragments (consumed one full step later)
            if (step + 1 < NSTEP) {
                const ushort* wnp = wchunk + (size_t)(k + 1) * STEP_ELEMS;
#pragma unroll
                for (int s = 0; s < 2; ++s)
#pragma unroll
                    for (int n = 0; n < 4; ++n)
                        bfr[nxt][s][n] = *(const short8*)(wnp + (n * 2 + s) * 512);
            }

            // per s: pack transient A-frag, feed its 4 MFMAs, advance basis
#pragma unroll
            for (int s = 0; s < 2; ++s) {
                union { ushort us[8]; short8 v; __hip_bfloat162 h2[4]; } pk;
#pragma unroll
                for (int e = 0; e < 8; e += 2) {
                    pk.h2[e >> 1] = __float22bfloat162_rn(
                        make_float2(p[s][e], p[s][e + 1]));
                }
#pragma unroll
                for (int n = 0; n < 4; ++n)
                    acc[n] = __builtin_amdgcn_mfma_f32_16x16x32_bf16(
                        pk.v, bfr[cur][s][n], acc[n], 0, 0, 0);
                if (k < NK - 1)
#pragma unroll
                    for (int e = 0; e < 8; ++e) p[s][e] *= r[s][e];
            }
        }

        // chunk boundary: reload x, rebuild basis (3 times total)
        if (ic < NCHUNK - 1) {
            LOAD_X(ic + 1);
            SETUP_BASIS();
        }
    }

    // ---- epilogue: C/D layout col=lane&15, row=(lane>>4)*4+reg ----
#pragma unroll
    for (int n = 0; n < 4; ++n) {
        int col   = cg * 64 + n * 16 + (lane & 15);
        int rbase = rb + (lane >> 4) * 4;
#pragma unroll
        for (int reg = 0; reg < 4; ++reg) {
            out[(size_t)(rbase + reg) * ODIM + col] = acc[n][reg];
        }
    }
#undef LOAD_X
#undef SETUP_BASIS
}

extern "C" void kernel_launch(void* const* d_in, const int* in_sizes, int n_in,
                              void* d_out, int out_size, void* d_ws, size_t ws_size,
                              hipStream_t stream) {
    const float* x       = (const float*)d_in[0];   // [B, I]
    const float* weights = (const float*)d_in[1];   // [O, I]
    const float* coeffs  = (const float*)d_in[2];   // [O, I, 9]
    float* out = (float*)d_out;                     // [B, O]
    ushort* wc = (ushort*)d_ws;                     // 36 * 32 KB = 1.13 MB

    prep_wc2<<<288, 256, 0, stream>>>(weights, coeffs, wc);
    bern_gemm<<<1024, 256, 0, stream>>>(x, wc, out);
}

// Round 7
// 97.797 us; speedup vs baseline: 3.7426x; 3.7426x over previous
//
#include <hip/hip_runtime.h>
#include <hip/hip_bf16.h>

// CustomBernsteinLayer: out[b,o] = sum_{i,k} ber[b,i,k] * (coeffs[o,i,k]*weights[o,i])
// ber = (1+t)^k (1-t)^(8-k), t = tanh(x).  With e = exp2(2x*log2e):
//   (1-t) = 2/(e+1) = q, ratio r = e, p0 = q^8, ber_{k+1} = ber_k * r.
// bf16 MFMA GEMM M=16384 N=256 K=2304, per-lane in-register A-gen (validated).
// Round 7: B deduplicated through LDS. R3-R5 proved per-wave global B loads
// (8 KB/step/wave through L1) are the wall; R6 proved tight launch-bounds
// spill to scratch (VGPR=64, WRITE 896 MB). Fix: 8-wave block shares one
// 64-col slice; B staged in 4-step groups (32 KB), double-buffered in 64 KB
// LDS via global_load_lds issued a full group ahead -> barrier drain hidden.
// ds_read_b128 fragment reads (stride-1, conflict-free). (512,2) bounds.

#define BDIM 16384
#define IDIM 256
#define ODIM 256
#define NK 9
#define NCHUNK 4
#define NSTEP 36
#define STEP_ELEMS (ODIM * 64)   // 16384 bf16 (32 KB) per K-step block
#define CGW 4                    // col-groups (256/64)

typedef short short8 __attribute__((ext_vector_type(8)));
typedef float floatx4 __attribute__((ext_vector_type(4)));

// ---------------------------------------------------------------------------
// prep (validated): wc[step][e] = bf16(coeffs[o,i,k]*weights[o,i]),
// e = (((o>>4)*2 + s)*64 + (o&15) + quad*16)*8 + j, i_local = s*32+quad*8+j,
// step = (i>>6)*9 + k. One coalesced 16B store per thread.
// ---------------------------------------------------------------------------
__global__ __launch_bounds__(256) void prep_wc2(const float* __restrict__ weights,
                                                const float* __restrict__ coeffs,
                                                ushort* __restrict__ wc) {
    int idx  = blockIdx.x * 256 + threadIdx.x;  // 73728 chunks
    int step = idx >> 11;
    int c    = idx & 2047;
    int big    = c >> 6;
    int lane_w = c & 63;
    int o    = (big >> 1) * 16 + (lane_w & 15);
    int s    = big & 1;
    int quad = lane_w >> 4;
    int ic = step / 9;
    int k  = step - ic * 9;
    int i0 = ic * 64 + s * 32 + quad * 8;

    const float* cp = coeffs + (size_t)(o * IDIM + i0) * NK + k;
    float4 w0 = *(const float4*)(weights + o * IDIM + i0);
    float4 w1 = *(const float4*)(weights + o * IDIM + i0 + 4);
    float wv[8] = {w0.x, w0.y, w0.z, w0.w, w1.x, w1.y, w1.z, w1.w};

    union { ushort us[8]; int4 v; __hip_bfloat162 h2[4]; } pk;
#pragma unroll
    for (int j = 0; j < 8; j += 2) {
        float a = cp[(size_t)j * NK] * wv[j];
        float b = cp[(size_t)(j + 1) * NK] * wv[j + 1];
        pk.h2[j >> 1] = __float22bfloat162_rn(make_float2(a, b));
    }
    *(int4*)(wc + (size_t)step * STEP_ELEMS + (size_t)c * 8) = pk.v;
}

// ---------------------------------------------------------------------------
// GEMM: 256 blocks x 512 threads (8 waves), 1 block/CU.
//   cg = blk & 3  -> cols cg*64 .. +63 (whole block)
//   rg = blk >> 2 -> wave w: rows rg*256 + w*32 .. +31
// Per-lane A state: rows rb + m*16 + (lane&15), m in {0,1};
//   i_local = s*32 + (lane>>4)*8 + j.
// B: cg-slice of each step is a contiguous 8 KB of wc; groups of 4 steps
// (32 KB) staged into Blds[2][32KB] one group ahead; fragment (n,s) of step
// g*4+k4 at Blds[g&1][k4*4096 + (n*2+s)*512 + lane*8], read as b128.
// ---------------------------------------------------------------------------
__global__ __launch_bounds__(512, 2) void bern_gemm(const float* __restrict__ x,
                                                    const ushort* __restrict__ wc,
                                                    float* __restrict__ out) {
    __shared__ ushort Blds[2][16384];   // 2 x 32 KB

    const int tid  = threadIdx.x;
    const int wave = tid >> 6;
    const int lane = tid & 63;
    const int cg   = blockIdx.x & 3;
    const int rb   = (blockIdx.x >> 2) * 256 + wave * 32;
    const int lrow = lane & 15;
    const int jseg = (lane >> 4) * 8;      // 0,8,16,24

    float p[2][2][8];   // [m][s][j]: raw x at chunk boundary, then running ber
    float r[2][2][8];   // ratio e = exp2(2x log2 e)
    floatx4 acc[2][4];
    floatx4 zero = {0.0f, 0.0f, 0.0f, 0.0f};
#pragma unroll
    for (int m = 0; m < 2; ++m)
#pragma unroll
        for (int n = 0; n < 4; ++n)
            acc[m][n] = zero;

#define LOAD_X(ic_)                                                             \
    {                                                                           \
        _Pragma("unroll") for (int m = 0; m < 2; ++m)                           \
        _Pragma("unroll") for (int s = 0; s < 2; ++s) {                         \
            const float* xp = x + (size_t)(rb + m * 16 + lrow) * IDIM           \
                              + (ic_) * 64 + s * 32 + jseg;                     \
            float4 v0 = *(const float4*)(xp);                                   \
            float4 v1 = *(const float4*)(xp + 4);                               \
            p[m][s][0] = v0.x; p[m][s][1] = v0.y;                               \
            p[m][s][2] = v0.z; p[m][s][3] = v0.w;                               \
            p[m][s][4] = v1.x; p[m][s][5] = v1.y;                               \
            p[m][s][6] = v1.z; p[m][s][7] = v1.w;                               \
        }                                                                       \
    }

#define SETUP_BASIS()                                                           \
    {                                                                           \
        _Pragma("unroll") for (int m = 0; m < 2; ++m)                           \
        _Pragma("unroll") for (int s = 0; s < 2; ++s)                           \
        _Pragma("unroll") for (int e = 0; e < 8; ++e) {                         \
            float t  = __builtin_amdgcn_exp2f(p[m][s][e] * 2.8853900817779268f);\
            float q  = 2.0f * __builtin_amdgcn_rcpf(t + 1.0f);                  \
            float q2 = q * q;                                                   \
            float q4 = q2 * q2;                                                 \
            p[m][s][e] = q4 * q4;                                               \
            r[m][s][e] = t;                                                     \
        }                                                                       \
    }

    // stage group g_ (4 steps, 32 KB cg-slice) into Blds[b_]; wave handles
    // sub-slice `wave` of each of the 4 steps (1 KB per global_load_lds).
#define STAGE(g_, b_)                                                           \
    {                                                                           \
        _Pragma("unroll") for (int q = 0; q < 4; ++q) {                         \
            int st  = (g_) * 4 + q;                                             \
            const ushort* sp = wc + (size_t)st * STEP_ELEMS + cg * 4096         \
                               + wave * 512 + lane * 8;                         \
            ushort* dp = &Blds[b_][(q * 8 + wave) * 512 + lane * 8];            \
            __builtin_amdgcn_global_load_lds(                                   \
                (const __attribute__((address_space(1))) void*)sp,              \
                (__attribute__((address_space(3))) void*)dp, 16, 0, 0);         \
        }                                                                       \
    }

    LOAD_X(0);
    SETUP_BASIS();
    STAGE(0, 0);

#pragma unroll
    for (int g = 0; g < 9; ++g) {
        __syncthreads();            // group g resident; prev buf free
        if (g < 8) STAGE(g + 1, (g + 1) & 1);

#pragma unroll
        for (int k4 = 0; k4 < 4; ++k4) {
            const int step = g * 4 + k4;
            // chunk boundary: rebuild basis (steps 9, 18, 27)
            if (step == 9 || step == 18 || step == 27) {
                LOAD_X(step / 9);
                SETUP_BASIS();
            }
            const int kin = step % 9;

#pragma unroll
            for (int s = 0; s < 2; ++s) {
                // B fragments for this (step, s) from LDS
                short8 bfr[4];
#pragma unroll
                for (int n = 0; n < 4; ++n)
                    bfr[n] = *(const short8*)&Blds[g & 1]
                        [k4 * 4096 + (n * 2 + s) * 512 + lane * 8];

#pragma unroll
                for (int m = 0; m < 2; ++m) {
                    union { ushort us[8]; short8 v; __hip_bfloat162 h2[4]; } pk;
#pragma unroll
                    for (int e = 0; e < 8; e += 2) {
                        pk.h2[e >> 1] = __float22bfloat162_rn(
                            make_float2(p[m][s][e], p[m][s][e + 1]));
                    }
#pragma unroll
                    for (int n = 0; n < 4; ++n)
                        acc[m][n] = __builtin_amdgcn_mfma_f32_16x16x32_bf16(
                            pk.v, bfr[n], acc[m][n], 0, 0, 0);
                    if (kin < NK - 1)
#pragma unroll
                        for (int e = 0; e < 8; ++e) p[m][s][e] *= r[m][s][e];
                }
            }
        }
    }

    // ---- epilogue: C/D layout col=lane&15, row=(lane>>4)*4+reg ----
#pragma unroll
    for (int m = 0; m < 2; ++m) {
#pragma unroll
        for (int n = 0; n < 4; ++n) {
            int col   = cg * 64 + n * 16 + (lane & 15);
            int rbase = rb + m * 16 + (lane >> 4) * 4;
#pragma unroll
            for (int reg = 0; reg < 4; ++reg) {
                out[(size_t)(rbase + reg) * ODIM + col] = acc[m][n][reg];
            }
        }
    }
#undef LOAD_X
#undef SETUP_BASIS
#undef STAGE
}

extern "C" void kernel_launch(void* const* d_in, const int* in_sizes, int n_in,
                              void* d_out, int out_size, void* d_ws, size_t ws_size,
                              hipStream_t stream) {
    const float* x       = (const float*)d_in[0];   // [B, I]
    const float* weights = (const float*)d_in[1];   // [O, I]
    const float* coeffs  = (const float*)d_in[2];   // [O, I, 9]
    float* out = (float*)d_out;                     // [B, O]
    ushort* wc = (ushort*)d_ws;                     // 36 * 32 KB = 1.13 MB

    prep_wc2<<<288, 256, 0, stream>>>(weights, coeffs, wc);
    bern_gemm<<<256, 512, 0, stream>>>(x, wc, out);
}